// Round 1
// baseline (106.952 us; speedup 1.0000x reference)
//
#include <hip/hip_runtime.h>

// Problem constants (B=1): flows [L,2,H,W] f32, images [L,C,H,W] f32,
// out [L,C,H,W] f32 with out[t] = sum_{k<=t} bilinear_sample(images[k], grid(t,k))
constexpr int L = 16, C = 8, H = 128, W = 128;
constexpr int HW = H * W;

// ---------------------------------------------------------------------------
// Kernel 1: cumulative sum of flows over L.  cum layout = [L][2][H][W]
// ---------------------------------------------------------------------------
__global__ __launch_bounds__(256) void cum_k(const float* __restrict__ flows,
                                             float* __restrict__ cum) {
    int idx = blockIdx.x * 256 + threadIdx.x;          // [0, 2*HW)
    if (idx >= 2 * HW) return;
    int comp = idx >> 14;                              // idx / HW
    int pix  = idx & (HW - 1);
    const float* src = flows + comp * HW + pix;
    float*       dst = cum   + comp * HW + pix;
    float s = 0.f;
#pragma unroll
    for (int l = 0; l < L; ++l) {
        s += src[(size_t)l * 2 * HW];
        dst[(size_t)l * 2 * HW] = s;
    }
}

// ---------------------------------------------------------------------------
// Kernel 2: transpose images [L][C][H][W] -> [L][H][W][C]  (32 B per pixel)
// ---------------------------------------------------------------------------
__global__ __launch_bounds__(256) void transpose_k(const float* __restrict__ images,
                                                   float* __restrict__ timg) {
    int idx = blockIdx.x * 256 + threadIdx.x;          // [0, L*HW)
    int l   = idx >> 14;
    int pix = idx & (HW - 1);
    const float* src = images + (size_t)l * C * HW + pix;
    float v0 = src[0 * HW], v1 = src[1 * HW], v2 = src[2 * HW], v3 = src[3 * HW];
    float v4 = src[4 * HW], v5 = src[5 * HW], v6 = src[6 * HW], v7 = src[7 * HW];
    float4* dst = reinterpret_cast<float4*>(timg) + (size_t)idx * 2;
    dst[0] = make_float4(v0, v1, v2, v3);
    dst[1] = make_float4(v4, v5, v6, v7);
}

// ---------------------------------------------------------------------------
// Kernel 3: main sampler. One thread per (t, h, w); loop k=0..t; 8-channel
// register accumulation; bilinear with zeros padding + periodic x wrap.
// ---------------------------------------------------------------------------
__global__ __launch_bounds__(256) void sample_k(const float* __restrict__ cum,
                                                const float* __restrict__ timg,
                                                float* __restrict__ out) {
    int t   = blockIdx.x >> 6;                         // 64 tiles of 256 px per t
    int pix = (blockIdx.x & 63) * 256 + threadIdx.x;
    int h = pix >> 7, w = pix & (W - 1);

    // base grid + 1 (work in the shifted domain: gx+1 in [0,2))
    float bx1 = (w + 0.5f) * (2.0f / W);
    float by1 = (h + 0.5f) * (2.0f / H);

    float ctx = cum[(size_t)(2 * t)     * HW + pix];
    float cty = cum[(size_t)(2 * t + 1) * HW + pix];

    float a0 = 0.f, a1 = 0.f, a2 = 0.f, a3 = 0.f;
    float a4 = 0.f, a5 = 0.f, a6 = 0.f, a7 = 0.f;

    for (int k = 0; k <= t; ++k) {
        float relx = ctx - cum[(size_t)(2 * k)     * HW + pix];
        float rely = cty - cum[(size_t)(2 * k + 1) * HW + pix];

        float xr = bx1 + relx;                 // = gx_unwrapped + 1
        float yr = by1 + rely;                 // = gy + 1
        // periodic wrap of x: remainder(xr, 2) = xr - 2*floor(xr/2)  -> [0,2)
        xr = fmaf(-2.0f, floorf(xr * 0.5f), xr);

        float ix = xr * (W * 0.5f) - 0.5f;     // (gx+1)*W/2 - 0.5
        float iy = yr * (H * 0.5f) - 0.5f;
        float x0f = floorf(ix), y0f = floorf(iy);
        float wx = ix - x0f,   wy = iy - y0f;

        const float4* img = reinterpret_cast<const float4*>(timg) + (size_t)k * HW * 2;

#pragma unroll
        for (int dy = 0; dy < 2; ++dy) {
#pragma unroll
            for (int dx = 0; dx < 2; ++dx) {
                float xf = x0f + (float)dx;
                float yf = y0f + (float)dy;
                bool valid = (xf >= 0.f) & (xf < (float)W) & (yf >= 0.f) & (yf < (float)H);
                float wgt = (dx ? wx : 1.f - wx) * (dy ? wy : 1.f - wy);
                wgt = valid ? wgt : 0.f;
                int xi = (int)xf; xi = xi < 0 ? 0 : (xi > W - 1 ? W - 1 : xi);
                int yi = (int)yf; yi = yi < 0 ? 0 : (yi > H - 1 ? H - 1 : yi);
                int off = (yi * W + xi) * 2;
                float4 p0 = img[off];
                float4 p1 = img[off + 1];
                a0 = fmaf(wgt, p0.x, a0);
                a1 = fmaf(wgt, p0.y, a1);
                a2 = fmaf(wgt, p0.z, a2);
                a3 = fmaf(wgt, p0.w, a3);
                a4 = fmaf(wgt, p1.x, a4);
                a5 = fmaf(wgt, p1.y, a5);
                a6 = fmaf(wgt, p1.z, a6);
                a7 = fmaf(wgt, p1.w, a7);
            }
        }
    }

    // store: out[t][c][h][w], coalesced per channel plane
    size_t obase = (size_t)t * C * HW + pix;
    out[obase + 0 * HW] = a0;
    out[obase + 1 * HW] = a1;
    out[obase + 2 * HW] = a2;
    out[obase + 3 * HW] = a3;
    out[obase + 4 * HW] = a4;
    out[obase + 5 * HW] = a5;
    out[obase + 6 * HW] = a6;
    out[obase + 7 * HW] = a7;
}

// ---------------------------------------------------------------------------
extern "C" void kernel_launch(void* const* d_in, const int* in_sizes, int n_in,
                              void* d_out, int out_size, void* d_ws, size_t ws_size,
                              hipStream_t stream) {
    const float* flows  = (const float*)d_in[0];   // [L,2,H,W]
    const float* images = (const float*)d_in[1];   // [L,C,H,W]
    float* out = (float*)d_out;                    // [L,C,H,W]

    float* cum  = (float*)d_ws;                    // 2*L*HW floats = 2 MB
    float* timg = cum + (size_t)2 * L * HW;        // L*HW*C floats = 8 MB

    cum_k<<<(2 * HW + 255) / 256, 256, 0, stream>>>(flows, cum);
    transpose_k<<<(L * HW) / 256, 256, 0, stream>>>(images, timg);
    sample_k<<<L * 64, 256, 0, stream>>>(cum, timg, out);
}

// Round 2
// 85.579 us; speedup vs baseline: 1.2497x; 1.2497x over previous
//
#include <hip/hip_runtime.h>
#include <hip/hip_fp16.h>

// B=1: flows [L,2,H,W] f32, images [L,C,H,W] f32, out [L,C,H,W] f32
// out[t] = sum_{k<=t} bilinear_sample(images[k], base_grid + cum[t]-cum[k])
constexpr int L = 16, C = 8, H = 128, W = 128;
constexpr int HW = H * W;

// ---------------------------------------------------------------------------
// Prep kernel (fused):
//   blocks [0, 1024):    transpose+convert images [L][C][H][W] f32 -> [L][HW][C] fp16
//   blocks [1024, 1152): cumsum flows over L -> cum [L][2][HW] f32
// ---------------------------------------------------------------------------
__global__ __launch_bounds__(256) void prep_k(const float* __restrict__ flows,
                                              const float* __restrict__ images,
                                              float* __restrict__ cum,
                                              __half* __restrict__ timg) {
    int b = blockIdx.x;
    constexpr int TB = (L * HW) / 256;                 // 1024 transpose blocks
    if (b < TB) {
        int idx = b * 256 + threadIdx.x;               // [0, L*HW)
        int l = idx >> 14, pix = idx & (HW - 1);
        const float* src = images + (size_t)l * C * HW + pix;
        float4 packed;
        __half2* hp = reinterpret_cast<__half2*>(&packed);
        hp[0] = __floats2half2_rn(src[0 * HW], src[1 * HW]);
        hp[1] = __floats2half2_rn(src[2 * HW], src[3 * HW]);
        hp[2] = __floats2half2_rn(src[4 * HW], src[5 * HW]);
        hp[3] = __floats2half2_rn(src[6 * HW], src[7 * HW]);
        reinterpret_cast<float4*>(timg)[idx] = packed;  // 16 B/pixel
    } else {
        int idx = (b - TB) * 256 + threadIdx.x;        // [0, 2*HW)
        int comp = idx >> 14, pix = idx & (HW - 1);
        const float* src = flows + comp * HW + pix;
        float* dst = cum + comp * HW + pix;
        float s = 0.f;
#pragma unroll
        for (int l = 0; l < L; ++l) {
            s += src[(size_t)l * 2 * HW];
            dst[(size_t)l * 2 * HW] = s;
        }
    }
}

// ---------------------------------------------------------------------------
// One bilinear sample of 8 fp16 channels, accumulated into float acc[8].
// Matches torch grid_sample(bilinear, zeros, align_corners=False) + x-wrap.
// ---------------------------------------------------------------------------
__device__ __forceinline__ void samp(float acc[8], float relx, float rely,
                                     float bx1, float by1,
                                     const __half* __restrict__ img) {
    float xr = bx1 + relx;                          // gx + 1 (unwrapped)
    xr = fmaf(-2.0f, floorf(xr * 0.5f), xr);        // remainder(xr,2) in [0,2)
    float yr = by1 + rely;                          // gy + 1
    float ix = xr * (W * 0.5f) - 0.5f;
    float iy = yr * (H * 0.5f) - 0.5f;
    float x0f = floorf(ix), y0f = floorf(iy);
    float wx = ix - x0f, wy = iy - y0f;
#pragma unroll
    for (int dy = 0; dy < 2; ++dy) {
#pragma unroll
        for (int dx = 0; dx < 2; ++dx) {
            float xf = x0f + (float)dx;
            float yf = y0f + (float)dy;
            bool valid = (xf >= 0.f) & (xf < (float)W) & (yf >= 0.f) & (yf < (float)H);
            float wgt = (dx ? wx : 1.f - wx) * (dy ? wy : 1.f - wy);
            wgt = valid ? wgt : 0.f;
            int xi = (int)xf; xi = xi < 0 ? 0 : (xi > W - 1 ? W - 1 : xi);
            int yi = (int)yf; yi = yi < 0 ? 0 : (yi > H - 1 ? H - 1 : yi);
            float4 raw = *reinterpret_cast<const float4*>(img + (yi * W + xi) * C);
            const __half* hv = reinterpret_cast<const __half*>(&raw);
#pragma unroll
            for (int c = 0; c < 8; ++c)
                acc[c] = fmaf(__half2float(hv[c]), wgt, acc[c]);  // v_fma_mix_f32
        }
    }
}

// ---------------------------------------------------------------------------
// Main sampler: each thread handles one pixel for the t-pair (p, 15-p)
// -> uniform 17 k-iterations per thread (perfect load balance).
// ---------------------------------------------------------------------------
constexpr int TPB = 128;
__global__ __launch_bounds__(TPB) void sample_k(const float* __restrict__ cum,
                                                const __half* __restrict__ timg,
                                                float* __restrict__ out) {
    int p   = blockIdx.x >> 7;                      // 8 pairs x 128 tiles
    int pix = (blockIdx.x & 127) * TPB + threadIdx.x;
    int h = pix >> 7, w = pix & (W - 1);
    float bx1 = (w + 0.5f) * (2.0f / W);
    float by1 = (h + 0.5f) * (2.0f / H);

    int t1 = p, t2 = 15 - p;                        // t1 < t2 always
    float c1x = cum[(size_t)(2 * t1)     * HW + pix];
    float c1y = cum[(size_t)(2 * t1 + 1) * HW + pix];
    float c2x = cum[(size_t)(2 * t2)     * HW + pix];
    float c2y = cum[(size_t)(2 * t2 + 1) * HW + pix];

    float acc1[8] = {0, 0, 0, 0, 0, 0, 0, 0};
    float acc2[8] = {0, 0, 0, 0, 0, 0, 0, 0};

    for (int k = 0; k <= t2; ++k) {
        float ckx = cum[(size_t)(2 * k)     * HW + pix];
        float cky = cum[(size_t)(2 * k + 1) * HW + pix];
        const __half* img = timg + (size_t)k * HW * C;
        samp(acc2, c2x - ckx, c2y - cky, bx1, by1, img);
        if (k <= t1)                                 // block-uniform branch
            samp(acc1, c1x - ckx, c1y - cky, bx1, by1, img);
    }

    size_t o1 = (size_t)t1 * C * HW + pix;
    size_t o2 = (size_t)t2 * C * HW + pix;
#pragma unroll
    for (int c = 0; c < 8; ++c) {
        out[o1 + c * HW] = acc1[c];
        out[o2 + c * HW] = acc2[c];
    }
}

// ---------------------------------------------------------------------------
extern "C" void kernel_launch(void* const* d_in, const int* in_sizes, int n_in,
                              void* d_out, int out_size, void* d_ws, size_t ws_size,
                              hipStream_t stream) {
    const float* flows  = (const float*)d_in[0];    // [L,2,H,W]
    const float* images = (const float*)d_in[1];    // [L,C,H,W]
    float* out = (float*)d_out;                     // [L,C,H,W]

    float*  cum  = (float*)d_ws;                    // 2*L*HW f32 = 2 MiB
    __half* timg = (__half*)((char*)d_ws + (size_t)2 * L * HW * sizeof(float)); // 4 MiB

    prep_k<<<(L * HW) / 256 + (2 * HW) / 256, 256, 0, stream>>>(flows, images, cum, timg);
    sample_k<<<8 * (HW / TPB), TPB, 0, stream>>>(cum, timg, out);
}